// Round 11
// baseline (446.505 us; speedup 1.0000x reference)
//
#include <hip/hip_runtime.h>

typedef _Float16 f16x8 __attribute__((ext_vector_type(8)));
typedef unsigned short ushort8 __attribute__((ext_vector_type(8)));
typedef float f32x4 __attribute__((ext_vector_type(4)));

#define C_IN     256
#define C_OUT    512
#define M_PTS    25000
#define KNN      16
#define P_BLK    4
#define ROWS     (P_BLK * KNN)   /* 64 */
#define ROWB     528             /* padded row stride in bytes (264 f16), 16B-aligned */
#define NTHREADS 256

#define MFMA16(a, b, c) __builtin_amdgcn_mfma_f32_16x16x32_f16(a, b, c, 0, 0, 0)

__device__ __forceinline__ unsigned short f2h(float f) {
    _Float16 h = (_Float16)f;
    return __builtin_bit_cast(unsigned short, h);
}

// Pack W [C_IN][C_OUT] f32 -> f16 in MFMA B-fragment order (verified):
// Wp[nt*4096 + kk*512 + lane*8 + j] = W[(kk*32 + (lane>>4)*8 + j)*C_OUT + nt*16 + (lane&15)]
__global__ void pack_w_kernel(const float* __restrict__ W, unsigned short* __restrict__ Wp) {
    int t = blockIdx.x * blockDim.x + threadIdx.x;   // 0 .. 131071
    int j    = t & 7;
    int lane = (t >> 3) & 63;
    int kk   = (t >> 9) & 7;
    int nt   = t >> 12;                               // 0..31
    int k = kk * 32 + ((lane >> 4) << 3) + j;
    int n = nt * 16 + (lane & 15);
    Wp[t] = f2h(W[k * C_OUT + n]);
}

// R9 kk-outer dataflow (PASSING, traffic-optimal) + two proven-safe knobs:
//  - LB(256,4): VGPR cap 128 -> occupancy ceiling 50% (R9's VGPR=100 at LB(,2)
//    gave only 21% resident waves; nothing hid the B-load latency chain)
//  - depth-1 named-scalar software prefetch of the next kk's B pair (no arrays,
//    no asm pins — both convicted of miscompiles in R6/R7/R10)
__global__ __launch_bounds__(NTHREADS, 4)
void fused_gather_ln_gemm_max(const float* __restrict__ x,
                              const int* __restrict__ idx,
                              const float* __restrict__ gamma,
                              const float* __restrict__ beta,
                              const unsigned short* __restrict__ Wp,
                              const float* __restrict__ bias,
                              float* __restrict__ out) {
    __shared__ char Ab[ROWS * ROWB];   // 33 KiB, f16 A-tile, padded rows, NO swizzle

    const int tid  = threadIdx.x;
    const int lane = tid & 63;
    const int wave = tid >> 6;
    const int m0   = blockIdx.x * P_BLK;

    // ---- Phase 1: gather + LayerNorm -> LDS (f16), unchanged from passing rounds ----
    float gm[16], bt[16];
    const int cg = (tid & 15) * 16;
    #pragma unroll
    for (int q = 0; q < 4; ++q) {
        float4 g4 = ((const float4*)(gamma + cg))[q];
        float4 b4 = ((const float4*)(beta  + cg))[q];
        gm[4*q+0] = g4.x; gm[4*q+1] = g4.y; gm[4*q+2] = g4.z; gm[4*q+3] = g4.w;
        bt[4*q+0] = b4.x; bt[4*q+1] = b4.y; bt[4*q+2] = b4.z; bt[4*q+3] = b4.w;
    }
    #pragma unroll
    for (int it = 0; it < ROWS / 16; ++it) {
        const int r  = it * 16 + (tid >> 4);
        const int xr = idx[m0 * KNN + r];
        const float4* xp = (const float4*)(x + (size_t)xr * C_IN) + (tid & 15) * 4;
        float vv[16];
        float s = 0.f, sq = 0.f;
        #pragma unroll
        for (int q = 0; q < 4; ++q) {
            float4 v4 = xp[q];
            vv[4*q+0] = v4.x; vv[4*q+1] = v4.y; vv[4*q+2] = v4.z; vv[4*q+3] = v4.w;
        }
        #pragma unroll
        for (int e = 0; e < 16; ++e) { s += vv[e]; sq += vv[e]*vv[e]; }
        #pragma unroll
        for (int o = 1; o < 16; o <<= 1) {
            s  += __shfl_xor(s, o);
            sq += __shfl_xor(sq, o);
        }
        const float mu  = s * (1.0f/256.0f);
        const float var = sq * (1.0f/256.0f) - mu * mu;
        const float rs  = rsqrtf(var + 1e-5f);
        ushort8 c0, c1;
        #pragma unroll
        for (int e = 0; e < 8; ++e) c0[e] = f2h((vv[e]   - mu)*rs*gm[e]   + bt[e]);
        #pragma unroll
        for (int e = 0; e < 8; ++e) c1[e] = f2h((vv[e+8] - mu)*rs*gm[e+8] + bt[e+8]);
        const int cb = (tid & 15) * 32;
        *(ushort8*)(Ab + r*ROWB + cb)      = c0;
        *(ushort8*)(Ab + r*ROWB + cb + 16) = c1;
    }
    __syncthreads();

    // ---- Phase 2: MFMA GEMM + fused max, kk-outer with depth-1 B prefetch ----
    const int rb0 = (0*16 + (lane & 15)) * ROWB;
    const int rb1 = (1*16 + (lane & 15)) * ROWB;
    const int rb2 = (2*16 + (lane & 15)) * ROWB;
    const int rb3 = (3*16 + (lane & 15)) * ROWB;
    const int csub = (lane >> 4) << 4;

    #pragma unroll 1
    for (int ntp = 0; ntp < 4; ++ntp) {
        const int nt0 = wave * 8 + ntp * 2;
        const int nt1 = nt0 + 1;
        const f16x8* Bp0 = (const f16x8*)Wp + (size_t)(nt0*8)*64 + lane;
        const f16x8* Bp1 = (const f16x8*)Wp + (size_t)(nt1*8)*64 + lane;

        f32x4 a00 = {0.f,0.f,0.f,0.f}, a01 = {0.f,0.f,0.f,0.f};
        f32x4 a10 = {0.f,0.f,0.f,0.f}, a11 = {0.f,0.f,0.f,0.f};
        f32x4 a20 = {0.f,0.f,0.f,0.f}, a21 = {0.f,0.f,0.f,0.f};
        f32x4 a30 = {0.f,0.f,0.f,0.f}, a31 = {0.f,0.f,0.f,0.f};

        // prefetch kk=0 pair
        f16x8 nb0 = Bp0[0*64];
        f16x8 nb1 = Bp1[0*64];

        #define KSTEP(KK)                                                   \
        {                                                                   \
            const f16x8 cb0 = nb0;                                          \
            const f16x8 cb1 = nb1;                                          \
            if ((KK) < 7) {                                                 \
                nb0 = Bp0[((KK)+1)*64];                                     \
                nb1 = Bp1[((KK)+1)*64];                                     \
            }                                                               \
            const int co = (KK)*64 + csub;                                  \
            const f16x8 fa0 = *(const f16x8*)(Ab + rb0 + co);               \
            const f16x8 fa1 = *(const f16x8*)(Ab + rb1 + co);               \
            const f16x8 fa2 = *(const f16x8*)(Ab + rb2 + co);               \
            const f16x8 fa3 = *(const f16x8*)(Ab + rb3 + co);               \
            a00 = MFMA16(fa0, cb0, a00);  a01 = MFMA16(fa0, cb1, a01);      \
            a10 = MFMA16(fa1, cb0, a10);  a11 = MFMA16(fa1, cb1, a11);      \
            a20 = MFMA16(fa2, cb0, a20);  a21 = MFMA16(fa2, cb1, a21);      \
            a30 = MFMA16(fa3, cb0, a30);  a31 = MFMA16(fa3, cb1, a31);      \
        }
        KSTEP(0)  KSTEP(1)  KSTEP(2)  KSTEP(3)
        KSTEP(4)  KSTEP(5)  KSTEP(6)  KSTEP(7)
        #undef KSTEP

        const float bias0 = bias[nt0*16 + (lane & 15)];
        const float bias1 = bias[nt1*16 + (lane & 15)];
        const int oc0 = nt0*16 + lane;   // valid when lane<16
        const int oc1 = nt1*16 + lane;

        float v0, v1;
        v0 = fmaxf(fmaxf(a00[0], a00[1]), fmaxf(a00[2], a00[3]));
        v1 = fmaxf(fmaxf(a01[0], a01[1]), fmaxf(a01[2], a01[3]));
        v0 = fmaxf(v0, __shfl_xor(v0, 16)); v0 = fmaxf(v0, __shfl_xor(v0, 32));
        v1 = fmaxf(v1, __shfl_xor(v1, 16)); v1 = fmaxf(v1, __shfl_xor(v1, 32));
        if (lane < 16) {
            out[(size_t)(m0 + 0) * C_OUT + oc0] = v0 + bias0;
            out[(size_t)(m0 + 0) * C_OUT + oc1] = v1 + bias1;
        }
        v0 = fmaxf(fmaxf(a10[0], a10[1]), fmaxf(a10[2], a10[3]));
        v1 = fmaxf(fmaxf(a11[0], a11[1]), fmaxf(a11[2], a11[3]));
        v0 = fmaxf(v0, __shfl_xor(v0, 16)); v0 = fmaxf(v0, __shfl_xor(v0, 32));
        v1 = fmaxf(v1, __shfl_xor(v1, 16)); v1 = fmaxf(v1, __shfl_xor(v1, 32));
        if (lane < 16) {
            out[(size_t)(m0 + 1) * C_OUT + oc0] = v0 + bias0;
            out[(size_t)(m0 + 1) * C_OUT + oc1] = v1 + bias1;
        }
        v0 = fmaxf(fmaxf(a20[0], a20[1]), fmaxf(a20[2], a20[3]));
        v1 = fmaxf(fmaxf(a21[0], a21[1]), fmaxf(a21[2], a21[3]));
        v0 = fmaxf(v0, __shfl_xor(v0, 16)); v0 = fmaxf(v0, __shfl_xor(v0, 32));
        v1 = fmaxf(v1, __shfl_xor(v1, 16)); v1 = fmaxf(v1, __shfl_xor(v1, 32));
        if (lane < 16) {
            out[(size_t)(m0 + 2) * C_OUT + oc0] = v0 + bias0;
            out[(size_t)(m0 + 2) * C_OUT + oc1] = v1 + bias1;
        }
        v0 = fmaxf(fmaxf(a30[0], a30[1]), fmaxf(a30[2], a30[3]));
        v1 = fmaxf(fmaxf(a31[0], a31[1]), fmaxf(a31[2], a31[3]));
        v0 = fmaxf(v0, __shfl_xor(v0, 16)); v0 = fmaxf(v0, __shfl_xor(v0, 32));
        v1 = fmaxf(v1, __shfl_xor(v1, 16)); v1 = fmaxf(v1, __shfl_xor(v1, 32));
        if (lane < 16) {
            out[(size_t)(m0 + 3) * C_OUT + oc0] = v0 + bias0;
            out[(size_t)(m0 + 3) * C_OUT + oc1] = v1 + bias1;
        }
    }
}

extern "C" void kernel_launch(void* const* d_in, const int* in_sizes, int n_in,
                              void* d_out, int out_size, void* d_ws, size_t ws_size,
                              hipStream_t stream) {
    const float* x     = (const float*)d_in[0];
    const int*   idx   = (const int*)d_in[1];
    const float* gamma = (const float*)d_in[2];
    const float* beta  = (const float*)d_in[3];
    const float* W     = (const float*)d_in[4];
    const float* b     = (const float*)d_in[5];
    float* out = (float*)d_out;
    unsigned short* Wp = (unsigned short*)d_ws;   // 256 KiB scratch

    hipLaunchKernelGGL(pack_w_kernel, dim3((C_IN * C_OUT) / 256), dim3(256), 0, stream, W, Wp);
    hipLaunchKernelGGL(fused_gather_ln_gemm_max, dim3(M_PTS / P_BLK), dim3(NTHREADS), 0, stream,
                       x, idx, gamma, beta, Wp, b, out);
}

// Round 12
// 256.188 us; speedup vs baseline: 1.7429x; 1.7429x over previous
//
#include <hip/hip_runtime.h>

typedef _Float16 f16x8 __attribute__((ext_vector_type(8)));
typedef unsigned short ushort8 __attribute__((ext_vector_type(8)));
typedef float f32x4 __attribute__((ext_vector_type(4)));

#define C_IN     256
#define C_OUT    512
#define M_PTS    25000
#define N_SRC    100000
#define KNN      16
#define P_BLK    4
#define ROWS     (P_BLK * KNN)   /* 64 */
#define ROWB     528             /* padded row stride in bytes (264 f16), 16B-aligned */
#define NTHREADS 256

#define MFMA16(a, b, c) __builtin_amdgcn_mfma_f32_16x16x32_f16(a, b, c, 0, 0, 0)

__device__ __forceinline__ unsigned short f2h(float f) {
    _Float16 h = (_Float16)f;
    return __builtin_bit_cast(unsigned short, h);
}

// Pack W [C_IN][C_OUT] f32 -> f16 in MFMA B-fragment order (verified):
// Wp[nt*4096 + kk*512 + lane*8 + j] = W[(kk*32 + (lane>>4)*8 + j)*C_OUT + nt*16 + (lane&15)]
__global__ void pack_w_kernel(const float* __restrict__ W, unsigned short* __restrict__ Wp) {
    int t = blockIdx.x * blockDim.x + threadIdx.x;   // 0 .. 131071
    int j    = t & 7;
    int lane = (t >> 3) & 63;
    int kk   = (t >> 9) & 7;
    int nt   = t >> 12;                               // 0..31
    int k = kk * 32 + ((lane >> 4) << 3) + j;
    int n = nt * 16 + (lane & 15);
    Wp[t] = f2h(W[k * C_OUT + n]);
}

// LN precompute: xn[i] = f16(LayerNorm(x[i])) for the 100K UNIQUE rows.
// The reference LNs each gathered occurrence (400K rows) — 4x redundant compute,
// 2x redundant gather bytes. Same math/rounding as the proven in-kernel phase 1.
__global__ __launch_bounds__(NTHREADS, 2)
void ln_rows_kernel(const float* __restrict__ x,
                    const float* __restrict__ gamma,
                    const float* __restrict__ beta,
                    unsigned short* __restrict__ xn) {
    const int tid = threadIdx.x;
    const int i   = blockIdx.x * 16 + (tid >> 4);    // source row
    const int c   = tid & 15;                        // 16-ch group within row
    float gm[16], bt[16];
    #pragma unroll
    for (int q = 0; q < 4; ++q) {
        float4 g4 = ((const float4*)(gamma + c * 16))[q];
        float4 b4 = ((const float4*)(beta  + c * 16))[q];
        gm[4*q+0] = g4.x; gm[4*q+1] = g4.y; gm[4*q+2] = g4.z; gm[4*q+3] = g4.w;
        bt[4*q+0] = b4.x; bt[4*q+1] = b4.y; bt[4*q+2] = b4.z; bt[4*q+3] = b4.w;
    }
    const float4* xp = (const float4*)(x + (size_t)i * C_IN) + c * 4;
    float vv[16];
    float s = 0.f, sq = 0.f;
    #pragma unroll
    for (int q = 0; q < 4; ++q) {
        float4 v4 = xp[q];
        vv[4*q+0] = v4.x; vv[4*q+1] = v4.y; vv[4*q+2] = v4.z; vv[4*q+3] = v4.w;
    }
    #pragma unroll
    for (int e = 0; e < 16; ++e) { s += vv[e]; sq += vv[e]*vv[e]; }
    #pragma unroll
    for (int o = 1; o < 16; o <<= 1) {
        s  += __shfl_xor(s, o);
        sq += __shfl_xor(sq, o);
    }
    const float mu  = s * (1.0f/256.0f);
    const float var = sq * (1.0f/256.0f) - mu * mu;
    const float rs  = rsqrtf(var + 1e-5f);
    ushort8 c0, c1;
    #pragma unroll
    for (int e = 0; e < 8; ++e) c0[e] = f2h((vv[e]   - mu)*rs*gm[e]   + bt[e]);
    #pragma unroll
    for (int e = 0; e < 8; ++e) c1[e] = f2h((vv[e+8] - mu)*rs*gm[e+8] + bt[e+8]);
    ushort8* dst = (ushort8*)(xn + (size_t)i * C_IN + c * 16);
    dst[0] = c0;
    dst[1] = c1;
}

// Main fused kernel: phase 1 = pure f16 gather-copy of precomputed xn rows (no VALU
// math); phase 2 = VERBATIM R9 kk-outer MFMA GEMM + max (passing, traffic-optimal).
// LB(256,3): cap ~170 >= need ~132 (R9's 100 arch + 32 acc) -> 3 blocks/CU without
// the R11 spill pathology (LB(,4): cap 128 < 132 -> scratch spills, 447us).
__global__ __launch_bounds__(NTHREADS, 3)
void fused_gather_gemm_max(const unsigned short* __restrict__ xn,
                           const int* __restrict__ idx,
                           const unsigned short* __restrict__ Wp,
                           const float* __restrict__ bias,
                           float* __restrict__ out) {
    __shared__ char Ab[ROWS * ROWB];   // 33 KiB, f16 A-tile, padded rows, NO swizzle

    const int tid  = threadIdx.x;
    const int lane = tid & 63;
    const int wave = tid >> 6;
    const int m0   = blockIdx.x * P_BLK;

    // ---- Phase 1: gather precomputed f16 rows -> LDS (32 B/thread/row) ----
    #pragma unroll
    for (int it = 0; it < ROWS / 16; ++it) {
        const int r  = it * 16 + (tid >> 4);
        const int xr = idx[m0 * KNN + r];
        const ushort8* sp = (const ushort8*)(xn + (size_t)xr * C_IN + (tid & 15) * 16);
        const ushort8 u0 = sp[0];
        const ushort8 u1 = sp[1];
        const int cb = (tid & 15) * 32;
        *(ushort8*)(Ab + r*ROWB + cb)      = u0;
        *(ushort8*)(Ab + r*ROWB + cb + 16) = u1;
    }
    __syncthreads();

    // ---- Phase 2: MFMA GEMM + fused max, kk-outer (VERBATIM R9) ----
    const int rb0 = (0*16 + (lane & 15)) * ROWB;
    const int rb1 = (1*16 + (lane & 15)) * ROWB;
    const int rb2 = (2*16 + (lane & 15)) * ROWB;
    const int rb3 = (3*16 + (lane & 15)) * ROWB;
    const int csub = (lane >> 4) << 4;

    #pragma unroll 1
    for (int ntp = 0; ntp < 4; ++ntp) {
        const int nt0 = wave * 8 + ntp * 2;
        const int nt1 = nt0 + 1;
        f32x4 a00 = {0.f,0.f,0.f,0.f}, a01 = {0.f,0.f,0.f,0.f};
        f32x4 a10 = {0.f,0.f,0.f,0.f}, a11 = {0.f,0.f,0.f,0.f};
        f32x4 a20 = {0.f,0.f,0.f,0.f}, a21 = {0.f,0.f,0.f,0.f};
        f32x4 a30 = {0.f,0.f,0.f,0.f}, a31 = {0.f,0.f,0.f,0.f};
        #pragma unroll
        for (int kk = 0; kk < 8; ++kk) {
            const f16x8 b0 = ((const f16x8*)Wp)[(nt0*8 + kk)*64 + lane];
            const f16x8 b1 = ((const f16x8*)Wp)[(nt1*8 + kk)*64 + lane];
            const int co = kk*64 + csub;
            const f16x8 fa0 = *(const f16x8*)(Ab + rb0 + co);
            const f16x8 fa1 = *(const f16x8*)(Ab + rb1 + co);
            const f16x8 fa2 = *(const f16x8*)(Ab + rb2 + co);
            const f16x8 fa3 = *(const f16x8*)(Ab + rb3 + co);
            a00 = MFMA16(fa0, b0, a00);  a01 = MFMA16(fa0, b1, a01);
            a10 = MFMA16(fa1, b0, a10);  a11 = MFMA16(fa1, b1, a11);
            a20 = MFMA16(fa2, b0, a20);  a21 = MFMA16(fa2, b1, a21);
            a30 = MFMA16(fa3, b0, a30);  a31 = MFMA16(fa3, b1, a31);
        }
        const float bias0 = bias[nt0*16 + (lane & 15)];
        const float bias1 = bias[nt1*16 + (lane & 15)];
        const int oc0 = nt0*16 + lane;   // valid when lane<16
        const int oc1 = nt1*16 + lane;

        float v0, v1;
        v0 = fmaxf(fmaxf(a00[0], a00[1]), fmaxf(a00[2], a00[3]));
        v1 = fmaxf(fmaxf(a01[0], a01[1]), fmaxf(a01[2], a01[3]));
        v0 = fmaxf(v0, __shfl_xor(v0, 16)); v0 = fmaxf(v0, __shfl_xor(v0, 32));
        v1 = fmaxf(v1, __shfl_xor(v1, 16)); v1 = fmaxf(v1, __shfl_xor(v1, 32));
        if (lane < 16) {
            out[(size_t)(m0 + 0) * C_OUT + oc0] = v0 + bias0;
            out[(size_t)(m0 + 0) * C_OUT + oc1] = v1 + bias1;
        }
        v0 = fmaxf(fmaxf(a10[0], a10[1]), fmaxf(a10[2], a10[3]));
        v1 = fmaxf(fmaxf(a11[0], a11[1]), fmaxf(a11[2], a11[3]));
        v0 = fmaxf(v0, __shfl_xor(v0, 16)); v0 = fmaxf(v0, __shfl_xor(v0, 32));
        v1 = fmaxf(v1, __shfl_xor(v1, 16)); v1 = fmaxf(v1, __shfl_xor(v1, 32));
        if (lane < 16) {
            out[(size_t)(m0 + 1) * C_OUT + oc0] = v0 + bias0;
            out[(size_t)(m0 + 1) * C_OUT + oc1] = v1 + bias1;
        }
        v0 = fmaxf(fmaxf(a20[0], a20[1]), fmaxf(a20[2], a20[3]));
        v1 = fmaxf(fmaxf(a21[0], a21[1]), fmaxf(a21[2], a21[3]));
        v0 = fmaxf(v0, __shfl_xor(v0, 16)); v0 = fmaxf(v0, __shfl_xor(v0, 32));
        v1 = fmaxf(v1, __shfl_xor(v1, 16)); v1 = fmaxf(v1, __shfl_xor(v1, 32));
        if (lane < 16) {
            out[(size_t)(m0 + 2) * C_OUT + oc0] = v0 + bias0;
            out[(size_t)(m0 + 2) * C_OUT + oc1] = v1 + bias1;
        }
        v0 = fmaxf(fmaxf(a30[0], a30[1]), fmaxf(a30[2], a30[3]));
        v1 = fmaxf(fmaxf(a31[0], a31[1]), fmaxf(a31[2], a31[3]));
        v0 = fmaxf(v0, __shfl_xor(v0, 16)); v0 = fmaxf(v0, __shfl_xor(v0, 32));
        v1 = fmaxf(v1, __shfl_xor(v1, 16)); v1 = fmaxf(v1, __shfl_xor(v1, 32));
        if (lane < 16) {
            out[(size_t)(m0 + 3) * C_OUT + oc0] = v0 + bias0;
            out[(size_t)(m0 + 3) * C_OUT + oc1] = v1 + bias1;
        }
    }
}

// ---------------- Fallback (ws too small): VERBATIM R8 passing kernel ----------------
__global__ __launch_bounds__(NTHREADS, 2)
void fused_fallback(const float* __restrict__ x,
                    const int* __restrict__ idx,
                    const float* __restrict__ gamma,
                    const float* __restrict__ beta,
                    const unsigned short* __restrict__ Wp,
                    const float* __restrict__ bias,
                    float* __restrict__ out) {
    __shared__ char Ab[ROWS * ROWB];
    const int tid  = threadIdx.x;
    const int lane = tid & 63;
    const int wave = tid >> 6;
    const int m0   = blockIdx.x * P_BLK;
    float gm[16], bt[16];
    const int cg = (tid & 15) * 16;
    #pragma unroll
    for (int q = 0; q < 4; ++q) {
        float4 g4 = ((const float4*)(gamma + cg))[q];
        float4 b4 = ((const float4*)(beta  + cg))[q];
        gm[4*q+0] = g4.x; gm[4*q+1] = g4.y; gm[4*q+2] = g4.z; gm[4*q+3] = g4.w;
        bt[4*q+0] = b4.x; bt[4*q+1] = b4.y; bt[4*q+2] = b4.z; bt[4*q+3] = b4.w;
    }
    #pragma unroll
    for (int it = 0; it < ROWS / 16; ++it) {
        const int r  = it * 16 + (tid >> 4);
        const int xr = idx[m0 * KNN + r];
        const float4* xp = (const float4*)(x + (size_t)xr * C_IN) + (tid & 15) * 4;
        float vv[16];
        float s = 0.f, sq = 0.f;
        #pragma unroll
        for (int q = 0; q < 4; ++q) {
            float4 v4 = xp[q];
            vv[4*q+0] = v4.x; vv[4*q+1] = v4.y; vv[4*q+2] = v4.z; vv[4*q+3] = v4.w;
        }
        #pragma unroll
        for (int e = 0; e < 16; ++e) { s += vv[e]; sq += vv[e]*vv[e]; }
        #pragma unroll
        for (int o = 1; o < 16; o <<= 1) { s += __shfl_xor(s, o); sq += __shfl_xor(sq, o); }
        const float mu  = s * (1.0f/256.0f);
        const float var = sq * (1.0f/256.0f) - mu * mu;
        const float rs  = rsqrtf(var + 1e-5f);
        ushort8 c0, c1;
        #pragma unroll
        for (int e = 0; e < 8; ++e) c0[e] = f2h((vv[e]   - mu)*rs*gm[e]   + bt[e]);
        #pragma unroll
        for (int e = 0; e < 8; ++e) c1[e] = f2h((vv[e+8] - mu)*rs*gm[e+8] + bt[e+8]);
        const int cb = (tid & 15) * 32;
        *(ushort8*)(Ab + r*ROWB + cb)      = c0;
        *(ushort8*)(Ab + r*ROWB + cb + 16) = c1;
    }
    __syncthreads();
    #pragma unroll 1
    for (int ntp = 0; ntp < 4; ++ntp) {
        const int nt0 = wave * 8 + ntp * 2;
        const int nt1 = nt0 + 1;
        f16x8 b0[8], b1[8];
        #pragma unroll
        for (int kk = 0; kk < 8; ++kk) {
            b0[kk] = ((const f16x8*)Wp)[(nt0*8 + kk)*64 + lane];
            b1[kk] = ((const f16x8*)Wp)[(nt1*8 + kk)*64 + lane];
        }
        const float bias0 = bias[nt0*16 + (lane & 15)];
        const float bias1 = bias[nt1*16 + (lane & 15)];
        #pragma unroll 1
        for (int p = 0; p < P_BLK; ++p) {
            const int r = p*16 + (lane & 15);
            const int rowbase = r * ROWB;
            f32x4 acc0 = {0.f,0.f,0.f,0.f}, acc1 = {0.f,0.f,0.f,0.f};
            #pragma unroll
            for (int kk = 0; kk < 8; ++kk) {
                f16x8 a = *(const f16x8*)(Ab + rowbase + kk*64 + ((lane >> 4) << 4));
                acc0 = MFMA16(a, b0[kk], acc0);
                acc1 = MFMA16(a, b1[kk], acc1);
            }
            float v0 = fmaxf(fmaxf(acc0[0], acc0[1]), fmaxf(acc0[2], acc0[3]));
            float v1 = fmaxf(fmaxf(acc1[0], acc1[1]), fmaxf(acc1[2], acc1[3]));
            v0 = fmaxf(v0, __shfl_xor(v0, 16)); v0 = fmaxf(v0, __shfl_xor(v0, 32));
            v1 = fmaxf(v1, __shfl_xor(v1, 16)); v1 = fmaxf(v1, __shfl_xor(v1, 32));
            if (lane < 16) {
                out[(size_t)(m0 + p) * C_OUT + nt0*16 + lane] = v0 + bias0;
                out[(size_t)(m0 + p) * C_OUT + nt1*16 + lane] = v1 + bias1;
            }
        }
    }
}

extern "C" void kernel_launch(void* const* d_in, const int* in_sizes, int n_in,
                              void* d_out, int out_size, void* d_ws, size_t ws_size,
                              hipStream_t stream) {
    const float* x     = (const float*)d_in[0];
    const int*   idx   = (const int*)d_in[1];
    const float* gamma = (const float*)d_in[2];
    const float* beta  = (const float*)d_in[3];
    const float* W     = (const float*)d_in[4];
    const float* b     = (const float*)d_in[5];
    float* out = (float*)d_out;

    const size_t xn_bytes = (size_t)N_SRC * C_IN * 2;          // 51.2 MB
    const size_t wp_bytes = (size_t)C_IN * C_OUT * 2;          // 256 KiB

    if (ws_size >= xn_bytes + wp_bytes) {
        unsigned short* xn = (unsigned short*)d_ws;
        unsigned short* Wp = (unsigned short*)((char*)d_ws + xn_bytes);
        hipLaunchKernelGGL(pack_w_kernel, dim3((C_IN * C_OUT) / 256), dim3(256), 0, stream, W, Wp);
        hipLaunchKernelGGL(ln_rows_kernel, dim3(N_SRC / 16), dim3(NTHREADS), 0, stream,
                           x, gamma, beta, xn);
        hipLaunchKernelGGL(fused_gather_gemm_max, dim3(M_PTS / P_BLK), dim3(NTHREADS), 0, stream,
                           xn, idx, Wp, b, out);
    } else {
        unsigned short* Wp = (unsigned short*)d_ws;            // 256 KiB
        hipLaunchKernelGGL(pack_w_kernel, dim3((C_IN * C_OUT) / 256), dim3(256), 0, stream, W, Wp);
        hipLaunchKernelGGL(fused_fallback, dim3(M_PTS / P_BLK), dim3(NTHREADS), 0, stream,
                           x, idx, gamma, beta, Wp, b, out);
    }
}